// Round 9
// baseline (80.637 us; speedup 1.0000x reference)
//
#include <hip/hip_runtime.h>

// d_ws layout:
//  uint2 wt[3408]: lo = half2(cos, sin) [X-dot], hi = half2(-sin, cos) [Y-dot]
//   [0..15]     conv1 (o*4 + dy*2 + dx)
//   [16..527]   conv2 (o*64 + c*16 + dy*4 + dx)   (legacy region, unused)
//   [528..3407] ff in (f,n) layout                 (legacy region, unused)
//  byte 27264: uint4 Btab[256] — MFMA B-fragments for stage 2:
//   entry e=(c*4+dy)*16+n holds 8 f16 (j -> dx=j>>1, comp=j&1);
//   col n: even -> X column (cos,sin), odd -> Y column (-sin,cos), o=n>>1.
//  byte 31360: uint2 ffT[60][48] — stage-3 lane-major FF table:
//   row l = n*6+g, col k -> feature f = g*48+k, angle ffw[f*10+n].
//   Each lane reads a contiguous 384 B run -> dwordx4 loads (R8 did 48
//   strided dwordx2 per lane).
#define WT_W1 0
#define WT_B2_BYTES (3408 * 8)
#define WT_FF_BYTES (WT_B2_BYTES + 4096)

typedef _Float16 h2  __attribute__((ext_vector_type(2)));
typedef _Float16 v8h __attribute__((ext_vector_type(8)));
typedef float    f4  __attribute__((ext_vector_type(4)));

__device__ __forceinline__ float fdot2(unsigned a, unsigned b, float c) {
    return __builtin_amdgcn_fdot2(__builtin_bit_cast(h2, a),
                                  __builtin_bit_cast(h2, b), c, false);
}
__device__ __forceinline__ unsigned packh2(float x, float y) {
    h2 h; h.x = (_Float16)x; h.y = (_Float16)y;
    return __builtin_bit_cast(unsigned, h);
}

__global__ void ringnn_setup(const float* __restrict__ w1,
                             const float* __restrict__ w2,
                             const float* __restrict__ ffw,
                             uint2* __restrict__ wt) {
    int t = blockIdx.x * blockDim.x + threadIdx.x;
    if (t < 3408) {
        float a;
        if (t < 16)        a = w1[t];
        else if (t < 528)  a = w2[t - 16];
        else               a = ffw[t - 528];
        float s, c;
        __sincosf(a, &s, &c);
        uint2 v;
        v.x = packh2(c, s);
        v.y = packh2(-s, c);
        wt[t] = v;
    } else if (t < 3408 + 256) {
        // MFMA B-fragment table for stage 2.
        const int e  = t - 3408;
        const int nn = e & 15;
        const int dy = (e >> 4) & 3;
        const int c  = e >> 6;
        const int o  = nn >> 1;
        unsigned d[4];
        #pragma unroll
        for (int dx = 0; dx < 4; ++dx) {
            float a = w2[o * 64 + c * 16 + dy * 4 + dx];
            float s, cc;
            __sincosf(a, &s, &cc);
            d[dx] = (nn & 1) ? packh2(-s, cc) : packh2(cc, s);
        }
        uint4* Bt = (uint4*)((char*)wt + WT_B2_BYTES);
        Bt[e] = make_uint4(d[0], d[1], d[2], d[3]);
    } else if (t < 3408 + 256 + 2880) {
        // Lane-major stage-3 FF table.
        const int e = t - 3664;
        const int l = e / 48;           // 0..59 = n*6+g
        const int k = e - l * 48;
        const int n = l / 6;
        const int g = l - n * 6;
        const int f = g * 48 + k;
        float a = ffw[f * 10 + n];
        float s, c;
        __sincosf(a, &s, &c);
        uint2 v;
        v.x = packh2(c, s);
        v.y = packh2(-s, c);
        ((uint2*)((char*)wt + WT_FF_BYTES))[l * 48 + k] = v;
    }
}

// 128 threads = 2 waves = 2 images per block; 2048 blocks -> 16 blocks/CU
// = 32 waves/CU. Stage 1: wave w -> image b0+w (fdot2, wave-uniform s_load
// weights). Stage 2: MFMA 16x16x32 f16 over the block's 72 positions.
// Stage 3: wave w -> image b0+w, blocked features, shfl reduction.
// NOTE: plain __launch_bounds__ — (256,8) caused catastrophic spill (R3).
__global__ __launch_bounds__(128) void ringnn_main(
    const float* __restrict__ x,
    const uint2* __restrict__ wt,
    float* __restrict__ out)
{
    __shared__ __align__(16) unsigned cs1[2][784];  // [img][c*196+i*14+j], half2
    __shared__ __align__(16) unsigned cs2[2][288];  // [img][(i*6+j)*8+o], half2

    const int t    = threadIdx.x;
    const int wv   = t >> 6;                // 0..1
    const int lane = t & 63;
    const int b0   = blockIdx.x * 2;
    const float* xb = x + (b0 + wv) * 784;

    // ---- Stage 1: sincos from global + 2x2/s2 conv, 1->4 ch (one wave) ----
    for (int pos = lane; pos < 196; pos += 64) {
        const int i = pos / 14;
        const int j = pos - i * 14;
        const float* px = xb + (2 * i) * 28 + 2 * j;
        float2 p0 = *(const float2*)(px);
        float2 p1 = *(const float2*)(px + 28);
        float s0, c0, s1, c1, s2, c2, s3, c3;
        __sincosf(p0.x, &s0, &c0);
        __sincosf(p0.y, &s1, &c1);
        __sincosf(p1.x, &s2, &c2);
        __sincosf(p1.y, &s3, &c3);
        unsigned v0 = packh2(c0, s0), v1 = packh2(c1, s1);
        unsigned v2 = packh2(c2, s2), v3 = packh2(c3, s3);
        #pragma unroll
        for (int o = 0; o < 4; ++o) {
            uint2 wa = wt[WT_W1 + o * 4 + 0], wb = wt[WT_W1 + o * 4 + 1];
            uint2 wc = wt[WT_W1 + o * 4 + 2], wd = wt[WT_W1 + o * 4 + 3];
            float X = 0.f, Y = 0.f;
            X = fdot2(v0, wa.x, X); Y = fdot2(v0, wa.y, Y);
            X = fdot2(v1, wb.x, X); Y = fdot2(v1, wb.y, Y);
            X = fdot2(v2, wc.x, X); Y = fdot2(v2, wc.y, Y);
            X = fdot2(v3, wd.x, X); Y = fdot2(v3, wd.y, Y);
            float rinv = rsqrtf(fmaxf(fmaf(X, X, Y * Y), 1e-30f));
            cs1[wv][o * 196 + pos] = packh2(X * rinv, Y * rinv);
        }
    }

    // B-fragments: entry (c*4+quad)*16+n -> index c*64 + lane: coalesced.
    const int n    = lane & 15;
    const int quad = lane >> 4;
    const uint4* Bt = (const uint4*)((const char*)wt + WT_B2_BYTES);
    uint4 bf0 = Bt[lane];
    uint4 bf1 = Bt[64 + lane];
    uint4 bf2 = Bt[128 + lane];
    uint4 bf3 = Bt[192 + lane];

    __syncthreads();

    // ---- Stage 2: MFMA. 72 positions (2 images x 36) = 5 tiles of 16 ----
    const unsigned* c1 = &cs1[0][0];
    for (int tile = wv; tile < 5; tile += 2) {
        const int p  = tile * 16 + n;
        const int pc = (p < 72) ? p : 71;          // clamp pad lanes (tile 4)
        const int im = (pc >= 36) ? 1 : 0;
        const int ps = pc - im * 36;
        const int i  = ps / 6;
        const int j  = ps - i * 6;
        // A row m=n -> position p; quad -> dy; 8 f16 = 16B of cs1 row.
        const unsigned base = (unsigned)(im * 784 + (2 * i + quad) * 14 + 2 * j);
        f4 acc = {0.f, 0.f, 0.f, 0.f};
        #pragma unroll
        for (int c = 0; c < 4; ++c) {
            uint2 lo = *(const uint2*)(c1 + base + c * 196);
            uint2 hi = *(const uint2*)(c1 + base + c * 196 + 2);
            uint4 a4 = make_uint4(lo.x, lo.y, hi.x, hi.y);
            v8h av = __builtin_bit_cast(v8h, a4);
            v8h bv = __builtin_bit_cast(v8h, (c == 0) ? bf0 : (c == 1) ? bf1
                                              : (c == 2) ? bf2 : bf3);
            acc = __builtin_amdgcn_mfma_f32_16x16x32_f16(av, bv, acc, 0, 0, 0);
        }
        // C/D: col = n, rows = quad*4 + r. X in even-n, Y in odd-n lanes.
        float pr0 = __shfl_xor(acc[0], 1);
        float pr1 = __shfl_xor(acc[1], 1);
        float pr2 = __shfl_xor(acc[2], 1);
        float pr3 = __shfl_xor(acc[3], 1);
        if (!(n & 1)) {
            const int o = n >> 1;
            float Xs[4] = {acc[0], acc[1], acc[2], acc[3]};
            float Ys[4] = {pr0, pr1, pr2, pr3};
            #pragma unroll
            for (int r = 0; r < 4; ++r) {
                const int p2 = tile * 16 + quad * 4 + r;
                if (p2 < 72) {
                    const int im2 = (p2 >= 36) ? 1 : 0;
                    const int ps2 = p2 - im2 * 36;
                    float X = Xs[r], Y = Ys[r];
                    float rinv = rsqrtf(fmaxf(fmaf(X, X, Y * Y), 1e-30f));
                    cs2[im2][ps2 * 8 + o] = packh2(X * rinv, Y * rinv);
                }
            }
        }
    }
    __syncthreads();

    // ---- Stage 3: ring-FF 288 -> 10 (one wave). lane = n3*6+g, 60 active;
    // blocked features f = g*48+k -> cs2 reads are 12x ds_read_b128 (6
    // distinct addrs x 10-way broadcast, conflict-free) and ffT reads are
    // 24x dwordx4 from a contiguous 384B per-lane run.
    {
        const int n3 = lane / 6;
        const int g  = lane - n3 * 6;
        const int ll = (n3 < 10) ? lane : 0;     // clamp idle lanes 60..63
        const uint4* c2v = (const uint4*)(&cs2[wv][(ll % 6) * 48]);
        const uint4* wf  = (const uint4*)((const char*)wt + WT_FF_BYTES) + ll * 24;
        float X0 = 0.f, Y0 = 0.f, X1 = 0.f, Y1 = 0.f;
        #pragma unroll
        for (int kk = 0; kk < 12; ++kk) {
            uint4 v4 = c2v[kk];
            uint4 wA = wf[kk * 2 + 0];           // features 4kk, 4kk+1
            uint4 wB = wf[kk * 2 + 1];           // features 4kk+2, 4kk+3
            if (kk & 1) {
                X1 = fdot2(v4.x, wA.x, X1); Y1 = fdot2(v4.x, wA.y, Y1);
                X1 = fdot2(v4.y, wA.z, X1); Y1 = fdot2(v4.y, wA.w, Y1);
                X1 = fdot2(v4.z, wB.x, X1); Y1 = fdot2(v4.z, wB.y, Y1);
                X1 = fdot2(v4.w, wB.z, X1); Y1 = fdot2(v4.w, wB.w, Y1);
            } else {
                X0 = fdot2(v4.x, wA.x, X0); Y0 = fdot2(v4.x, wA.y, Y0);
                X0 = fdot2(v4.y, wA.z, X0); Y0 = fdot2(v4.y, wA.w, Y0);
                X0 = fdot2(v4.z, wB.x, X0); Y0 = fdot2(v4.z, wB.y, Y0);
                X0 = fdot2(v4.w, wB.z, X0); Y0 = fdot2(v4.w, wB.w, Y0);
            }
        }
        float X = X0 + X1, Y = Y0 + Y1;
        // 6-lane group sum: p=v+sh3(v); r=p+sh1(p)+sh2(p)  (valid at g==0)
        float pX = X + __shfl_down(X, 3);
        float pY = Y + __shfl_down(Y, 3);
        float sX = pX + __shfl_down(pX, 1) + __shfl_down(pX, 2);
        float sY = pY + __shfl_down(pY, 1) + __shfl_down(pY, 2);
        if (g == 0 && n3 < 10) {
            float rinv = rsqrtf(fmaxf(fmaf(sX, sX, sY * sY), 1e-30f));
            out[(b0 + wv) * 10 + n3] = sY * rinv;
        }
    }
}

extern "C" void kernel_launch(void* const* d_in, const int* in_sizes, int n_in,
                              void* d_out, int out_size, void* d_ws, size_t ws_size,
                              hipStream_t stream) {
    const float* x   = (const float*)d_in[0];
    const float* w1  = (const float*)d_in[1];
    const float* w2  = (const float*)d_in[2];
    const float* ffw = (const float*)d_in[3];
    uint2* wt = (uint2*)d_ws;              // needs 31360 + 23040 = 54400 bytes
    float* o  = (float*)d_out;

    ringnn_setup<<<26, 256, 0, stream>>>(w1, w2, ffw, wt);
    ringnn_main<<<2048, 128, 0, stream>>>(x, wt, o);
}

// Round 10
// 76.166 us; speedup vs baseline: 1.0587x; 1.0587x over previous
//
#include <hip/hip_runtime.h>

// d_ws layout:
//  uint2 wt[3408]: lo = half2(cos, sin) [X-dot], hi = half2(-sin, cos) [Y-dot]
//   [0..15]     conv1 (o*4 + dy*2 + dx)
//   [16..527]   conv2 (o*64 + c*16 + dy*4 + dx)   (legacy, unused by main)
//   [528..3407] ff    (f*10 + n)
//  byte 27264: uint4 Btab[256] — MFMA B-fragments for stage 2:
//   entry e=(c*4+dy)*16+n holds 8 f16 (j -> dx=j>>1, comp=j&1);
//   col n: even -> X column (cos,sin), odd -> Y column (-sin,cos), o=n>>1.
#define WT_W1 0
#define WT_FF 528
#define WT_B2_BYTES (3408 * 8)

typedef _Float16 h2  __attribute__((ext_vector_type(2)));
typedef _Float16 v8h __attribute__((ext_vector_type(8)));
typedef float    f4  __attribute__((ext_vector_type(4)));

__device__ __forceinline__ float fdot2(unsigned a, unsigned b, float c) {
    return __builtin_amdgcn_fdot2(__builtin_bit_cast(h2, a),
                                  __builtin_bit_cast(h2, b), c, false);
}
__device__ __forceinline__ unsigned packh2(float x, float y) {
    h2 h; h.x = (_Float16)x; h.y = (_Float16)y;
    return __builtin_bit_cast(unsigned, h);
}

__global__ void ringnn_setup(const float* __restrict__ w1,
                             const float* __restrict__ w2,
                             const float* __restrict__ ffw,
                             uint2* __restrict__ wt) {
    int t = blockIdx.x * blockDim.x + threadIdx.x;
    if (t < 3408) {
        float a;
        if (t < 16)        a = w1[t];
        else if (t < 528)  a = w2[t - 16];
        else               a = ffw[t - 528];
        float s, c;
        __sincosf(a, &s, &c);
        uint2 v;
        v.x = packh2(c, s);
        v.y = packh2(-s, c);
        wt[t] = v;
    } else if (t < 3408 + 256) {
        // MFMA B-fragment table for stage 2.
        const int e  = t - 3408;
        const int nn = e & 15;
        const int dy = (e >> 4) & 3;
        const int c  = e >> 6;
        const int o  = nn >> 1;
        unsigned d[4];
        #pragma unroll
        for (int dx = 0; dx < 4; ++dx) {
            float a = w2[o * 64 + c * 16 + dy * 4 + dx];
            float s, cc;
            __sincosf(a, &s, &cc);
            d[dx] = (nn & 1) ? packh2(-s, cc) : packh2(cc, s);
        }
        uint4* Bt = (uint4*)((char*)wt + WT_B2_BYTES);
        Bt[e] = make_uint4(d[0], d[1], d[2], d[3]);
    }
}

// 256 threads = 4 waves; 2 images per block; grid 2048 -> 8192 waves =
// 32 waves/CU (hardware cap; R8's 128-thread blocks only reached 16/CU).
// Stage 1: 2 waves (128 lanes) per image -> serial chain halved vs R8.
// Stage 2: MFMA 16x16x32 f16, 5 M-tiles over 72 positions, spread on 4 waves.
// Stage 3: 2 waves per image, 5 outputs/wave, 12-lane groups, 24-iter chain
//          (half of R8), in-wave shfl reduction.
// NOTE: plain __launch_bounds__ — (256,8) caused catastrophic spill (R3).
__global__ __launch_bounds__(256) void ringnn_main(
    const float* __restrict__ x,
    const uint2* __restrict__ wt,
    float* __restrict__ out)
{
    __shared__ __align__(16) unsigned cs1[2][784];  // [img][c*196+i*14+j], half2
    __shared__ __align__(16) unsigned cs2[2][288];  // [img][(i*6+j)*8+o], half2

    const int t     = threadIdx.x;
    const int wave  = t >> 6;               // 0..3
    const int lane  = t & 63;
    const int img   = t >> 7;               // 0..1 (stages 1,3)
    const int tid   = t & 127;              // lane within the image's 2 waves
    const int b0    = blockIdx.x * 2;
    const float* xb = x + (b0 + img) * 784;

    // ---- Stage 1: sincos from global + 2x2/s2 conv, 1->4 ch ----
    // 128 lanes per image -> at most 2 iterations of the pos loop.
    for (int pos = tid; pos < 196; pos += 128) {
        const int i = pos / 14;
        const int j = pos - i * 14;
        const float* px = xb + (2 * i) * 28 + 2 * j;
        float2 p0 = *(const float2*)(px);
        float2 p1 = *(const float2*)(px + 28);
        float s0, c0, s1, c1, s2, c2, s3, c3;
        __sincosf(p0.x, &s0, &c0);
        __sincosf(p0.y, &s1, &c1);
        __sincosf(p1.x, &s2, &c2);
        __sincosf(p1.y, &s3, &c3);
        unsigned v0 = packh2(c0, s0), v1 = packh2(c1, s1);
        unsigned v2 = packh2(c2, s2), v3 = packh2(c3, s3);
        #pragma unroll
        for (int o = 0; o < 4; ++o) {
            uint2 wa = wt[WT_W1 + o * 4 + 0], wb = wt[WT_W1 + o * 4 + 1];
            uint2 wc = wt[WT_W1 + o * 4 + 2], wd = wt[WT_W1 + o * 4 + 3];
            float X = 0.f, Y = 0.f;
            X = fdot2(v0, wa.x, X); Y = fdot2(v0, wa.y, Y);
            X = fdot2(v1, wb.x, X); Y = fdot2(v1, wb.y, Y);
            X = fdot2(v2, wc.x, X); Y = fdot2(v2, wc.y, Y);
            X = fdot2(v3, wd.x, X); Y = fdot2(v3, wd.y, Y);
            float rinv = rsqrtf(fmaxf(fmaf(X, X, Y * Y), 1e-30f));
            cs1[img][o * 196 + pos] = packh2(X * rinv, Y * rinv);
        }
    }

    // B-fragments: entry (c*4+quad)*16+n -> index c*64 + lane: coalesced.
    const int n    = lane & 15;
    const int quad = lane >> 4;
    const uint4* Bt = (const uint4*)((const char*)wt + WT_B2_BYTES);
    uint4 bf0 = Bt[lane];
    uint4 bf1 = Bt[64 + lane];
    uint4 bf2 = Bt[128 + lane];
    uint4 bf3 = Bt[192 + lane];

    __syncthreads();

    // ---- Stage 2: MFMA. 72 positions (2 images x 36) = 5 tiles of 16 ----
    const unsigned* c1 = &cs1[0][0];
    for (int tile = wave; tile < 5; tile += 4) {
        const int p  = tile * 16 + n;
        const int pc = (p < 72) ? p : 71;          // clamp pad lanes (tile 4)
        const int im = (pc >= 36) ? 1 : 0;
        const int ps = pc - im * 36;
        const int i  = ps / 6;
        const int j  = ps - i * 6;
        // A row m=n -> position p; quad -> dy; 8 f16 = 16B of cs1 row.
        const unsigned base = (unsigned)(im * 784 + (2 * i + quad) * 14 + 2 * j);
        f4 acc = {0.f, 0.f, 0.f, 0.f};
        #pragma unroll
        for (int c = 0; c < 4; ++c) {
            uint2 lo = *(const uint2*)(c1 + base + c * 196);
            uint2 hi = *(const uint2*)(c1 + base + c * 196 + 2);
            uint4 a4 = make_uint4(lo.x, lo.y, hi.x, hi.y);
            v8h av = __builtin_bit_cast(v8h, a4);
            v8h bv = __builtin_bit_cast(v8h, (c == 0) ? bf0 : (c == 1) ? bf1
                                              : (c == 2) ? bf2 : bf3);
            acc = __builtin_amdgcn_mfma_f32_16x16x32_f16(av, bv, acc, 0, 0, 0);
        }
        // C/D: col = n, rows = quad*4 + r. X in even-n, Y in odd-n lanes.
        float pr0 = __shfl_xor(acc[0], 1);
        float pr1 = __shfl_xor(acc[1], 1);
        float pr2 = __shfl_xor(acc[2], 1);
        float pr3 = __shfl_xor(acc[3], 1);
        if (!(n & 1)) {
            const int o = n >> 1;
            float Xs[4] = {acc[0], acc[1], acc[2], acc[3]};
            float Ys[4] = {pr0, pr1, pr2, pr3};
            #pragma unroll
            for (int r = 0; r < 4; ++r) {
                const int p2 = tile * 16 + quad * 4 + r;
                if (p2 < 72) {
                    const int im2 = (p2 >= 36) ? 1 : 0;
                    const int ps2 = p2 - im2 * 36;
                    float X = Xs[r], Y = Ys[r];
                    float rinv = rsqrtf(fmaxf(fmaf(X, X, Y * Y), 1e-30f));
                    cs2[im2][ps2 * 8 + o] = packh2(X * rinv, Y * rinv);
                }
            }
        }
    }
    __syncthreads();

    // ---- Stage 3: ring-FF 288 -> 10 (2 waves/image, 5 outputs per wave) ----
    // wave half = wave&1: outputs n3 = half*5 + lane/12; g = lane%12 (60
    // active lanes); features f = g + 12k, k<24 (24-iter chain, half of R8).
    // cs2 reads: 12 distinct consecutive words x 5-way broadcast = no
    // conflicts. 12-lane groups sit fully inside one wave -> shfl reduce.
    {
        const int half = wave & 1;
        const int nl   = lane / 12;              // 0..4 active
        const int g    = lane - nl * 12;
        float X = 0.f, Y = 0.f;
        if (nl < 5) {
            const int n3 = half * 5 + nl;
            #pragma unroll 6
            for (int k = 0; k < 24; ++k) {
                const int f = g + 12 * k;
                unsigned v = cs2[img][f];
                uint2 wvv = wt[WT_FF + f * 10 + n3];
                X = fdot2(v, wvv.x, X);
                Y = fdot2(v, wvv.y, Y);
            }
        }
        // 12-lane group sum (valid at g==0): q = v+sh4+sh8; s = q+sh1+sh2+sh3
        float qX = X + __shfl_down(X, 4) + __shfl_down(X, 8);
        float qY = Y + __shfl_down(Y, 4) + __shfl_down(Y, 8);
        float sX = qX + __shfl_down(qX, 1) + __shfl_down(qX, 2) + __shfl_down(qX, 3);
        float sY = qY + __shfl_down(qY, 1) + __shfl_down(qY, 2) + __shfl_down(qY, 3);
        if (g == 0 && nl < 5) {
            const int n3 = half * 5 + nl;
            float rinv = rsqrtf(fmaxf(fmaf(sX, sX, sY * sY), 1e-30f));
            out[(b0 + img) * 10 + n3] = sY * rinv;
        }
    }
}

extern "C" void kernel_launch(void* const* d_in, const int* in_sizes, int n_in,
                              void* d_out, int out_size, void* d_ws, size_t ws_size,
                              hipStream_t stream) {
    const float* x   = (const float*)d_in[0];
    const float* w1  = (const float*)d_in[1];
    const float* w2  = (const float*)d_in[2];
    const float* ffw = (const float*)d_in[3];
    uint2* wt = (uint2*)d_ws;              // needs 27264 + 4096 = 31360 bytes
    float* o  = (float*)d_out;

    ringnn_setup<<<15, 256, 0, stream>>>(w1, w2, ffw, wt);
    ringnn_main<<<2048, 256, 0, stream>>>(x, wt, o);
}